// Round 5
// baseline (119039.685 us; speedup 1.0000x reference)
//
#include <hip/hip_runtime.h>
#include <math.h>

// Seq2seq GRU encoder/decoder with exact JAX threefry sampling.
// R6 design: persistent + fenceless sc1 barriers + LDS tiles (R5 base) +
//   (1) ROTATED staging order: R4 FETCH_SIZE 8.97GB == issued staging bytes
//       proved concurrent same-line sc1 misses from 32 WGs don't merge ->
//       all go to HBM (32x amplification + queue delays ~20us/phase).
//       Rotating each WG's chunk start (wgi&7) de-synchronizes the lines:
//       first toucher allocates L3, rest hit. Bitwise-identical values.
//   (2) 3-phase pipelined decoder step: hh-dots for step d+1 are computed
//       during step d's C-window (their inputs h1(d+1)/h2(d+1) are ready
//       after P1/P2). Critical path keeps only ih-dots + combines.
//   (3) C1 fused into C23: the 8 C-WGs compute hid from the staged sY tile
//       (same k-ascending chain) -> one less barrier, no hid round-trip.
//   Every fma chain/combine/sampling expression is verbatim from the
//   passing R4 kernel -> absmax must stay exactly 1.525879e-05.

#define BB 64
#define TT 512
#define VV 390
#define EE 256
#define HH 512

// swizzled state layout: elem (k, b) at [(k>>2)*256 + b*4 + (k&3)]
#define SW(k, b) ((((k) >> 2) << 8) + ((b) << 2) + ((k) & 3))

static __device__ __forceinline__ void tf2x32(unsigned k0, unsigned k1,
                                              unsigned x0, unsigned x1,
                                              unsigned &o0, unsigned &o1) {
  unsigned ks2 = k0 ^ k1 ^ 0x1BD11BDAu;
  x0 += k0; x1 += k1;
#define TFR(r) x0 += x1; x1 = (x1 << (r)) | (x1 >> (32 - (r))); x1 ^= x0;
  TFR(13) TFR(15) TFR(26) TFR(6)
  x0 += k1; x1 += ks2 + 1u;
  TFR(17) TFR(29) TFR(16) TFR(24)
  x0 += ks2; x1 += k0 + 2u;
  TFR(13) TFR(15) TFR(26) TFR(6)
  x0 += k0; x1 += k1 + 3u;
  TFR(17) TFR(29) TFR(16) TFR(24)
  x0 += k1; x1 += ks2 + 4u;
  TFR(13) TFR(15) TFR(26) TFR(6)
  x0 += ks2; x1 += k0 + 5u;
#undef TFR
  o0 = x0; o1 = x1;
}

static __device__ __forceinline__ float sigm(float x) {
  return 1.0f / (1.0f + expf(-x));
}

// ---- agent-scope relaxed (sc1) helpers: coherent at L3, no fences ----
static __device__ __forceinline__ unsigned ldu_a(const unsigned* p) {
  return __hip_atomic_load((unsigned*)p, __ATOMIC_RELAXED,
                           __HIP_MEMORY_SCOPE_AGENT);
}
static __device__ __forceinline__ void stu_a(unsigned* p, unsigned v) {
  __hip_atomic_store(p, v, __ATOMIC_RELAXED, __HIP_MEMORY_SCOPE_AGENT);
}
static __device__ __forceinline__ void stf_a(float* p, float v) {
  stu_a((unsigned*)p, __float_as_uint(v));
}
static __device__ __forceinline__ float2 ldf2_a(const float* p) {
  unsigned long long v = __hip_atomic_load((unsigned long long*)p,
      __ATOMIC_RELAXED, __HIP_MEMORY_SCOPE_AGENT);
  return make_float2(__uint_as_float((unsigned)v),
                     __uint_as_float((unsigned)(v >> 32)));
}

// Stage X[all 512 k][b0..b0+7] (16KB) into LDS, chunk order rotated by
// `rot` so concurrent WGs of a group touch DIFFERENT lines at any instant
// (first toucher allocates L3, rest hit). Values/slots identical.
static __device__ __forceinline__ void stage512(const float* X, int b0,
                                                float2* L, int rot) {
  int tid = threadIdx.x;
  float2 v[8];
#pragma unroll
  for (int r = 0; r < 8; ++r) {
    int idx = tid + (((r + rot) & 7) << 8);
    v[r] = ldf2_a(X + ((idx >> 4) << 8) + ((b0 + ((idx >> 1) & 7)) << 2) +
                  ((idx & 1) << 1));
  }
#pragma unroll
  for (int r = 0; r < 8; ++r) {
    int idx = tid + (((r + rot) & 7) << 8);
    L[idx] = v[r];
  }
}

// 3-row dot over a staged LDS tile (K floats), lane's batch = bi.
// fma order identical to R3/R4 (k ascending, u.x..u.w).
template <int K>
static __device__ __forceinline__ void dot3_lds(const float4* Lx, int bi,
    const float* __restrict__ w0, const float* __restrict__ w1,
    const float* __restrict__ w2, float &r0, float &r1, float &r2) {
  const float4* q0 = (const float4*)w0;
  const float4* q1 = (const float4*)w1;
  const float4* q2 = (const float4*)w2;
  float s0 = 0.f, s1 = 0.f, s2 = 0.f;
#pragma unroll
  for (int k4 = 0; k4 < (K >> 2); ++k4) {
    float4 x = Lx[(k4 << 3) + bi];
    float4 u0 = q0[k4], u1 = q1[k4], u2 = q2[k4];
    s0 = fmaf(x.x, u0.x, s0); s0 = fmaf(x.y, u0.y, s0); s0 = fmaf(x.z, u0.z, s0); s0 = fmaf(x.w, u0.w, s0);
    s1 = fmaf(x.x, u1.x, s1); s1 = fmaf(x.y, u1.y, s1); s1 = fmaf(x.z, u1.z, s1); s1 = fmaf(x.w, u1.w, s1);
    s2 = fmaf(x.x, u2.x, s2); s2 = fmaf(x.y, u2.y, s2); s2 = fmaf(x.z, u2.z, s2); s2 = fmaf(x.w, u2.w, s2);
  }
  r0 = s0; r1 = s1; r2 = s2;
}

template <int K>
static __device__ __forceinline__ float dot1_lds(const float4* Lx, int bi,
    const float* __restrict__ w) {
  const float4* q = (const float4*)w;
  float s = 0.f;
#pragma unroll
  for (int k4 = 0; k4 < (K >> 2); ++k4) {
    float4 x = Lx[(k4 << 3) + bi];
    float4 u = q[k4];
    s = fmaf(x.x, u.x, s); s = fmaf(x.y, u.y, s);
    s = fmaf(x.z, u.z, s); s = fmaf(x.w, u.w, s);
  }
  return s;
}

// 3-row dot over SWIZZLED read-only X (plain cached float4) — encoder xT.
template <int K>
static __device__ __forceinline__ void dot3s_p(const float* __restrict__ X, int b,
    const float* __restrict__ w0, const float* __restrict__ w1,
    const float* __restrict__ w2, float &r0, float &r1, float &r2) {
  const float4* q0 = (const float4*)w0;
  const float4* q1 = (const float4*)w1;
  const float4* q2 = (const float4*)w2;
  const float4* Xp = (const float4*)X;
  float s0 = 0.f, s1 = 0.f, s2 = 0.f;
#pragma unroll
  for (int k4 = 0; k4 < (K >> 2); ++k4) {
    float4 x = Xp[(k4 << 6) + b];
    float4 u0 = q0[k4], u1 = q1[k4], u2 = q2[k4];
    s0 = fmaf(x.x, u0.x, s0); s0 = fmaf(x.y, u0.y, s0); s0 = fmaf(x.z, u0.z, s0); s0 = fmaf(x.w, u0.w, s0);
    s1 = fmaf(x.x, u1.x, s1); s1 = fmaf(x.y, u1.y, s1); s1 = fmaf(x.z, u1.z, s1); s1 = fmaf(x.w, u1.w, s1);
    s2 = fmaf(x.x, u2.x, s2); s2 = fmaf(x.y, u2.y, s2); s2 = fmaf(x.z, u2.z, s2); s2 = fmaf(x.w, u2.w, s2);
  }
  r0 = s0; r1 = s1; r2 = s2;
}

// Per-lane contiguous row (embedding gather, read-only) — unchanged order.
template <int K>
static __device__ __forceinline__ void dot3_row(const float* __restrict__ xrow,
    const float* __restrict__ w0, const float* __restrict__ w1,
    const float* __restrict__ w2, float &r0, float &r1, float &r2) {
  const float4* xq = (const float4*)xrow;
  const float4* q0 = (const float4*)w0;
  const float4* q1 = (const float4*)w1;
  const float4* q2 = (const float4*)w2;
  float s0 = 0.f, s1 = 0.f, s2 = 0.f;
#pragma unroll
  for (int k4 = 0; k4 < (K >> 2); ++k4) {
    float4 x = xq[k4];
    float4 u0 = q0[k4], u1 = q1[k4], u2 = q2[k4];
    s0 = fmaf(x.x, u0.x, s0); s0 = fmaf(x.y, u0.y, s0); s0 = fmaf(x.z, u0.z, s0); s0 = fmaf(x.w, u0.w, s0);
    s1 = fmaf(x.x, u1.x, s1); s1 = fmaf(x.y, u1.y, s1); s1 = fmaf(x.z, u1.z, s1); s1 = fmaf(x.w, u1.w, s1);
    s2 = fmaf(x.x, u2.x, s2); s2 = fmaf(x.y, u2.y, s2); s2 = fmaf(x.z, u2.z, s2); s2 = fmaf(x.w, u2.w, s2);
  }
  r0 = s0; r1 = s1; r2 = s2;
}

// Group-local fenceless barrier (flags = group's own lines). Entry
// __syncthreads drains vmcnt -> this WG's sc1 stores are coherent before
// its flag publishes them. s_sleep backoff cuts L3 poll pressure.
static __device__ __forceinline__ void gbar(unsigned* f, int nwg, int wgi,
                                            unsigned ep) {
  __syncthreads();
  int tid = threadIdx.x;
  if (tid == 0) stu_a(f + wgi, ep);
  if (tid < 64) {
    bool done = false;
    while (!done) {
      bool ok = true;
      for (int i = tid; i < nwg; i += 64) ok &= (ldu_a(f + i) >= ep);
      done = __all((int)ok);
      if (!done) __builtin_amdgcn_s_sleep(1);
    }
  }
  __syncthreads();
}

__global__ __launch_bounds__(256) void k_init(float* out,
    float* h1buf, float* h2buf, int* tok, unsigned* ebase) {
  int wg = blockIdx.x, tid = threadIdx.x;
  for (int i = wg * 256 + tid; i < HH * BB; i += 64 * 256) {
    h1buf[i] = 0.f;  // slot 0 only (slot 1 always written before read)
    h2buf[i] = 0.f;
  }
  for (int v = tid; v < VV; v += 256)
    out[(size_t)wg * TT * VV + v] = (v == 388) ? 1.0f : 0.0f;
  if (wg == 0) {  // encoder flags: 8 groups x 64 = 512 words
    ebase[tid] = 0u;
    ebase[tid + 256] = 0u;
  }
  if (tid == 0) {
    out[(size_t)BB * TT * VV + (size_t)wg * TT] = 388.0f;
    tok[wg] = 388;
  }
}

// x_swz[t][(e>>2)*256 + b*4 + (e&3)] = sum_v input[b][t][v]*emb[v][e].
__global__ __launch_bounds__(256) void k_xgemm(const float* __restrict__ input,
    const float* __restrict__ emb, float* __restrict__ xT) {
  int t = blockIdx.x, tid = threadIdx.x;
  int s = tid >> 6, b = tid & 63;
  __shared__ float lin[64 * 65];
  float4 acc[16];
#pragma unroll
  for (int i = 0; i < 16; ++i) acc[i] = make_float4(0.f, 0.f, 0.f, 0.f);
  for (int k0 = 0; k0 < VV; k0 += 64) {
    int kmax = min(64, VV - k0);
    __syncthreads();
#pragma unroll
    for (int r = 0; r < 16; ++r) {
      int idx = r * 256 + tid;
      int b2 = idx >> 6, kk = idx & 63;
      if (kk < kmax)
        lin[kk * 65 + b2] = input[((size_t)b2 * TT + t) * VV + k0 + kk];
    }
    __syncthreads();
    for (int kk = 0; kk < kmax; ++kk) {
      float xv = lin[kk * 65 + b];
      const float4* er = (const float4*)(emb + (size_t)(k0 + kk) * EE);
#pragma unroll
      for (int i = 0; i < 16; ++i) {
        float4 w = er[s + 4 * i];
        acc[i].x = fmaf(xv, w.x, acc[i].x);
        acc[i].y = fmaf(xv, w.y, acc[i].y);
        acc[i].z = fmaf(xv, w.z, acc[i].z);
        acc[i].w = fmaf(xv, w.w, acc[i].w);
      }
    }
  }
  float* dst0 = xT + (size_t)t * (EE * 64);
#pragma unroll
  for (int i = 0; i < 16; ++i)
    *(float4*)(dst0 + (s + 4 * i) * 256 + 4 * b) = acc[i];
}

// Persistent encoder: 512 WGs = 8 groups x (32 layer0-WGs + 32 layer1-WGs).
// Unchanged from R4 except rotated staging + sleep-backoff barrier.
__global__ __launch_bounds__(256, 2) void k_enc(
    const float* xT, float* h1buf, float* h2buf,
    const float* __restrict__ Wih0, const float* __restrict__ Whh0,
    const float* __restrict__ bih0, const float* __restrict__ bhh0,
    const float* __restrict__ Wih1, const float* __restrict__ Whh1,
    const float* __restrict__ bih1, const float* __restrict__ bhh1,
    unsigned* eflags, unsigned* dflags) {
  int wg = blockIdx.x, tid = threadIdx.x;
  int g = wg >> 6, wgi = wg & 63;
  int b0 = g << 3;
  int lay = wgi >> 5, j0 = (wgi & 31) << 4;
  int task = tid >> 7, l = tid & 127;
  int jj = l >> 3, bi = l & 7;
  int j = j0 + jj, b = b0 + bi;
  int rot = wg & 7;
  __shared__ float2 sX[2048];
  __shared__ float2 sY[2048];
  __shared__ float part[3][128];
  unsigned* gf = eflags + (g << 6);
  for (int t = 0; t <= TT; ++t) {
    const float* h1_r = h1buf + (t & 1) * (HH * BB);        // h1[t-1]
    float* h1_w = h1buf + ((t + 1) & 1) * (HH * BB);        // h1[t]
    if (lay == 0) {
      if (t < TT) {
        stage512(h1_r, b0, sX, rot);
        __syncthreads();
        float ar = 0.f, az = 0.f, an = 0.f;
        if (task == 0) {
          dot3s_p<EE>(xT + (size_t)t * (EE * 64), b,
                      Wih0 + (size_t)j * EE, Wih0 + (size_t)(512 + j) * EE,
                      Wih0 + (size_t)(1024 + j) * EE, ar, az, an);
        } else {
          float hr, hz, hn;
          dot3_lds<HH>((const float4*)sX, bi,
                       Whh0 + (size_t)j * HH, Whh0 + (size_t)(512 + j) * HH,
                       Whh0 + (size_t)(1024 + j) * HH, hr, hz, hn);
          part[0][l] = hr; part[1][l] = hz; part[2][l] = hn;
        }
        __syncthreads();
        if (task == 0) {
          float hr = part[0][l], hz = part[1][l], hn = part[2][l];
          float r = sigm((ar + bih0[j]) + (hr + bhh0[j]));
          float z = sigm((az + bih0[512 + j]) + (hz + bhh0[512 + j]));
          float n = tanhf((an + bih0[1024 + j]) + r * (hn + bhh0[1024 + j]));
          float hp = ((const float*)sX)[((j >> 2) << 5) + (bi << 2) + (j & 3)];
          stf_a(h1_w + SW(j, b), (1.0f - z) * n + z * hp);
        }
      }
    } else {
      if (t >= 1) {  // layer1 processes step t-1
        const float* h2_r = h2buf + ((t + 1) & 1) * (HH * BB);  // h2[t-2]
        float* h2_w = h2buf + (t & 1) * (HH * BB);              // h2[t-1]
        stage512(h1_r, b0, sX, rot);
        stage512(h2_r, b0, sY, rot);
        __syncthreads();
        float ar = 0.f, az = 0.f, an = 0.f;
        if (task == 0) {
          dot3_lds<HH>((const float4*)sX, bi,   // input = h1[t-1]
                       Wih1 + (size_t)j * HH, Wih1 + (size_t)(512 + j) * HH,
                       Wih1 + (size_t)(1024 + j) * HH, ar, az, an);
        } else {
          float hr, hz, hn;
          dot3_lds<HH>((const float4*)sY, bi,
                       Whh1 + (size_t)j * HH, Whh1 + (size_t)(512 + j) * HH,
                       Whh1 + (size_t)(1024 + j) * HH, hr, hz, hn);
          part[0][l] = hr; part[1][l] = hz; part[2][l] = hn;
        }
        __syncthreads();
        if (task == 0) {
          float hr = part[0][l], hz = part[1][l], hn = part[2][l];
          float r = sigm((ar + bih1[j]) + (hr + bhh1[j]));
          float z = sigm((az + bih1[512 + j]) + (hz + bhh1[512 + j]));
          float n = tanhf((an + bih1[1024 + j]) + r * (hn + bhh1[1024 + j]));
          float hp = ((const float*)sY)[((j >> 2) << 5) + (bi << 2) + (j & 3)];
          stf_a(h2_w + SW(j, b), (1.0f - z) * n + z * hp);
        }
      }
    }
    // Zero this group's decoder flags (overlay xT floats [g*32, g*32+32)).
    if (t == 2 && wgi == 0 && tid < 32) stu_a(dflags + (g << 5) + tid, 0u);
    if (t < TT) gbar(gf, 64, wgi, (unsigned)(t + 1));
  }
}

// Persistent decoder: 256 WGs = 8 groups x 32 WGs (16 j-cols each).
// 3 phases/step: P1 = A-ih + combine (hh from pA precomputed),
// P2 = B-ih + combine (hh from pB), P3 = C (8 WGs) ∥ hh-precompute for d+1.
__global__ __launch_bounds__(256, 1) void k_dec(
    float* h1buf, float* h2buf,
    const float* __restrict__ demb,
    const float* __restrict__ dWih0, const float* __restrict__ dWhh0,
    const float* __restrict__ dbih0, const float* __restrict__ dbhh0,
    const float* __restrict__ dWih1, const float* __restrict__ dWhh1,
    const float* __restrict__ dbih1, const float* __restrict__ dbhh1,
    const float* __restrict__ Wp1, const float* __restrict__ bp1,
    const float* __restrict__ Wp2, const float* __restrict__ bp2,
    float* out, int* tok, unsigned* dflags) {
  int wg = blockIdx.x, tid = threadIdx.x;
  int g = wg >> 5, wgi = wg & 31;
  int b0 = g << 3, j0 = wgi << 4;
  int task = tid >> 7, l = tid & 127;
  int jj = l >> 3, bi = l & 7;
  int j = j0 + jj, b = b0 + bi;
  int rot = wgi & 7;
  __shared__ float2 sX[2048];   // h1 tile (staged in P2, reused P1/P3 next)
  __shared__ float2 sY[2048];   // h2 tile (staged in P3, reused P2 next)
  __shared__ float pA[3][128];  // precomputed A-hh partials
  __shared__ float pB[3][128];  // precomputed B-hh partials
  __shared__ __align__(16) float lhid[HH];
  __shared__ float rf[8];
  __shared__ int ri[4];
  __shared__ int ltok[8];
  unsigned* gf = dflags + (g << 5);
  unsigned rk0 = 0u, rk1 = 42u;  // jax.random.key(42), chained in registers
  unsigned ep = 0u;
  // ---- prologue: stage zero states, precompute hh-partials for d=0 ----
  stage512(h1buf, b0, sX, rot);  // slot 0 = zeros (k_init)
  stage512(h2buf, b0, sY, rot);
  __syncthreads();
  if (task == 1) {
    float hr, hz, hn;
    dot3_lds<HH>((const float4*)sX, bi,
                 dWhh0 + (size_t)j * HH, dWhh0 + (size_t)(512 + j) * HH,
                 dWhh0 + (size_t)(1024 + j) * HH, hr, hz, hn);
    pA[0][l] = hr; pA[1][l] = hz; pA[2][l] = hn;
  } else {
    float hr, hz, hn;
    dot3_lds<HH>((const float4*)sY, bi,
                 dWhh1 + (size_t)j * HH, dWhh1 + (size_t)(512 + j) * HH,
                 dWhh1 + (size_t)(1024 + j) * HH, hr, hz, hn);
    pB[0][l] = hr; pB[1][l] = hz; pB[2][l] = hn;
  }
  __syncthreads();
  for (int d = 0; d < TT - 1; ++d) {
    float* h1_w = h1buf + ((d + 1) & 1) * (HH * BB);
    float* h2_w = h2buf + ((d + 1) & 1) * (HH * BB);
    // ---- P1: A = ih-dot + combine (hh precomputed in pA) ----
    if (tid < 8) ltok[tid] = (int)ldu_a((const unsigned*)tok + b0 + tid);
    __syncthreads();
    if (task == 0) {
      int tk = ltok[bi];
      float ar, az, an;
      dot3_row<EE>(demb + (size_t)tk * EE,
                   dWih0 + (size_t)j * EE, dWih0 + (size_t)(512 + j) * EE,
                   dWih0 + (size_t)(1024 + j) * EE, ar, az, an);
      float hr = pA[0][l], hz = pA[1][l], hn = pA[2][l];
      float r = sigm((ar + dbih0[j]) + (hr + dbhh0[j]));
      float z = sigm((az + dbih0[512 + j]) + (hz + dbhh0[512 + j]));
      float n = tanhf((an + dbih0[1024 + j]) + r * (hn + dbhh0[1024 + j]));
      float hp = ((const float*)sX)[((j >> 2) << 5) + (bi << 2) + (j & 3)];
      stf_a(h1_w + SW(j, b), (1.0f - z) * n + z * hp);
    }
    gbar(gf, 32, wgi, ++ep);
    // ---- P2: B = ih-dot(h1') + combine (hh precomputed in pB) ----
    stage512(h1_w, b0, sX, rot);   // sX <- h1(d+1); also feeds P1(d+1)/P3
    __syncthreads();
    if (task == 0) {
      float ar, az, an;
      dot3_lds<HH>((const float4*)sX, bi,
                   dWih1 + (size_t)j * HH, dWih1 + (size_t)(512 + j) * HH,
                   dWih1 + (size_t)(1024 + j) * HH, ar, az, an);
      float hr = pB[0][l], hz = pB[1][l], hn = pB[2][l];
      float r = sigm((ar + dbih1[j]) + (hr + dbhh1[j]));
      float z = sigm((az + dbih1[512 + j]) + (hz + dbhh1[512 + j]));
      float n = tanhf((an + dbih1[1024 + j]) + r * (hn + dbhh1[1024 + j]));
      float hp = ((const float*)sY)[((j >> 2) << 5) + (bi << 2) + (j & 3)];
      stf_a(h2_w + SW(j, b), (1.0f - z) * n + z * hp);
    }
    gbar(gf, 32, wgi, ++ep);
    // ---- P3: stage h2(d+1); C on 8 WGs; all WGs precompute hh(d+1) ----
    stage512(h2_w, b0, sY, rot);   // sY <- h2(d+1); feeds P2(d+1) + C + pB
    __syncthreads();
    if (wgi < 8) {
      int brow = b0 + wgi;  // bi index of brow within this group = wgi
      // hid = LeakyReLU(Wp1 . h2') from the staged sY tile (same chain)
      {
        float a = dot1_lds<HH>((const float4*)sY, wgi, Wp1 + (size_t)tid * HH);
        a += bp1[tid];
        lhid[tid] = (a >= 0.f) ? a : 0.1f * a;
        float a2 = dot1_lds<HH>((const float4*)sY, wgi,
                                Wp1 + (size_t)(tid + 256) * HH);
        a2 += bp1[tid + 256];
        lhid[tid + 256] = (a2 >= 0.f) ? a2 : 0.1f * a2;
      }
      __syncthreads();
      float v0 = 0.f, v1 = 0.f;
      if (tid < VV) {
        const float4* w = (const float4*)(Wp2 + (size_t)tid * HH);
        float a = 0.f;
#pragma unroll 8
        for (int k4 = 0; k4 < HH / 4; ++k4) {
          float4 q = w[k4];
          float4 hv = *(const float4*)&lhid[k4 * 4];
          a = fmaf(hv.x, q.x, a); a = fmaf(hv.y, q.y, a);
          a = fmaf(hv.z, q.z, a); a = fmaf(hv.w, q.w, a);
        }
        v0 = a + bp2[tid];
      }
      if (tid + 256 < VV) {
        const float4* w = (const float4*)(Wp2 + (size_t)(tid + 256) * HH);
        float a = 0.f;
#pragma unroll 8
        for (int k4 = 0; k4 < HH / 4; ++k4) {
          float4 q = w[k4];
          float4 hv = *(const float4*)&lhid[k4 * 4];
          a = fmaf(hv.x, q.x, a); a = fmaf(hv.y, q.y, a);
          a = fmaf(hv.z, q.z, a); a = fmaf(hv.w, q.w, a);
        }
        v1 = a + bp2[tid + 256];
      }
      // row max (same reduction order as R4)
      float m = -INFINITY;
      if (tid < VV) m = fmaxf(m, v0);
      if (tid + 256 < VV) m = fmaxf(m, v1);
      for (int off = 32; off > 0; off >>= 1) m = fmaxf(m, __shfl_down(m, off, 64));
      if ((tid & 63) == 0) rf[tid >> 6] = m;
      __syncthreads();
      if (tid == 0) rf[4] = fmaxf(fmaxf(rf[0], rf[1]), fmaxf(rf[2], rf[3]));
      __syncthreads();
      m = rf[4];
      // sk = TF(rng_d, (0,1)); gumbel-argmax (first-index ties)
      unsigned sk0, sk1;
      tf2x32(rk0, rk1, 0u, 1u, sk0, sk1);
      float by = -INFINITY; int bc = 0x7fffffff;
      if (tid < VV) {
        unsigned o0, o1;
        tf2x32(sk0, sk1, 0u, (unsigned)(brow * VV + tid), o0, o1);
        unsigned bits = o0 ^ o1;
        float f = __uint_as_float(0x3f800000u | (bits >> 9)) - 1.0f;
        float u = (f > 0.f) ? f : 1.17549435e-38f;
        float gg = (float)(-log(-log((double)u)));
        float y = v0 + gg;
        if (y > by || (y == by && tid < bc)) { by = y; bc = tid; }
      }
      if (tid + 256 < VV) {
        int c = tid + 256;
        unsigned o0, o1;
        tf2x32(sk0, sk1, 0u, (unsigned)(brow * VV + c), o0, o1);
        unsigned bits = o0 ^ o1;
        float f = __uint_as_float(0x3f800000u | (bits >> 9)) - 1.0f;
        float u = (f > 0.f) ? f : 1.17549435e-38f;
        float gg = (float)(-log(-log((double)u)));
        float y = v1 + gg;
        if (y > by || (y == by && c < bc)) { by = y; bc = c; }
      }
      for (int off = 32; off > 0; off >>= 1) {
        float oy = __shfl_down(by, off, 64);
        int oc = __shfl_down(bc, off, 64);
        if (oy > by || (oy == by && oc < bc)) { by = oy; bc = oc; }
      }
      if ((tid & 63) == 0) { rf[tid >> 6] = by; ri[tid >> 6] = bc; }
      __syncthreads();
      if (tid == 0) {
        by = rf[0]; bc = ri[0];
        for (int w2 = 1; w2 < 4; ++w2)
          if (rf[w2] > by || (rf[w2] == by && ri[w2] < bc)) { by = rf[w2]; bc = ri[w2]; }
        stu_a((unsigned*)tok + brow, (unsigned)bc);
        out[(size_t)BB * TT * VV + (size_t)brow * TT + (d + 1)] = (float)bc;
      }
      __syncthreads();
      // softmax probs
      float e0 = 0.f, e1 = 0.f, ssum = 0.f;
      if (tid < VV) { e0 = expf(v0 - m); ssum += e0; }
      if (tid + 256 < VV) { e1 = expf(v1 - m); ssum += e1; }
      for (int off = 32; off > 0; off >>= 1) ssum += __shfl_down(ssum, off, 64);
      if ((tid & 63) == 0) rf[tid >> 6] = ssum;
      __syncthreads();
      if (tid == 0) rf[4] = (rf[0] + rf[1]) + (rf[2] + rf[3]);
      __syncthreads();
      float S = rf[4];
      float* orow = out + ((size_t)brow * TT + (d + 1)) * VV;
      if (tid < VV) orow[tid] = e0 / S;
      if (tid + 256 < VV) orow[tid + 256] = e1 / S;
      __syncthreads();
    }
    // precompute hh-partials for step d+1 (inputs h1(d+1)=sX, h2(d+1)=sY)
    if (task == 1) {
      float hr, hz, hn;
      dot3_lds<HH>((const float4*)sX, bi,
                   dWhh0 + (size_t)j * HH, dWhh0 + (size_t)(512 + j) * HH,
                   dWhh0 + (size_t)(1024 + j) * HH, hr, hz, hn);
      pA[0][l] = hr; pA[1][l] = hz; pA[2][l] = hn;
    } else {
      float hr, hz, hn;
      dot3_lds<HH>((const float4*)sY, bi,
                   dWhh1 + (size_t)j * HH, dWhh1 + (size_t)(512 + j) * HH,
                   dWhh1 + (size_t)(1024 + j) * HH, hr, hz, hn);
      pB[0][l] = hr; pB[1][l] = hz; pB[2][l] = hn;
    }
    // all WGs advance the key chain identically
    {
      unsigned n0, n1;
      tf2x32(rk0, rk1, 0u, 0u, n0, n1);
      rk0 = n0; rk1 = n1;
    }
    gbar(gf, 32, wgi, ++ep);
  }
}

extern "C" void kernel_launch(void* const* d_in, const int* in_sizes, int n_in,
                              void* d_out, int out_size, void* d_ws, size_t ws_size,
                              hipStream_t stream) {
  (void)in_sizes; (void)n_in; (void)out_size; (void)ws_size;
  const float* input = (const float*)d_in[0];
  const float* e_emb = (const float*)d_in[1];
  const float* eWih0 = (const float*)d_in[2];
  const float* eWhh0 = (const float*)d_in[3];
  const float* ebih0 = (const float*)d_in[4];
  const float* ebhh0 = (const float*)d_in[5];
  const float* eWih1 = (const float*)d_in[6];
  const float* eWhh1 = (const float*)d_in[7];
  const float* ebih1 = (const float*)d_in[8];
  const float* ebhh1 = (const float*)d_in[9];
  const float* d_emb = (const float*)d_in[10];
  const float* dWih0 = (const float*)d_in[11];
  const float* dWhh0 = (const float*)d_in[12];
  const float* dbih0 = (const float*)d_in[13];
  const float* dbhh0 = (const float*)d_in[14];
  const float* dWih1 = (const float*)d_in[15];
  const float* dWhh1 = (const float*)d_in[16];
  const float* dbih1 = (const float*)d_in[17];
  const float* dbhh1 = (const float*)d_in[18];
  const float* Wp1   = (const float*)d_in[19];
  const float* bp1   = (const float*)d_in[20];
  const float* Wp2   = (const float*)d_in[21];
  const float* bp2   = (const float*)d_in[22];
  float* out = (float*)d_out;

  // ws layout (unchanged): xT [512][256*64] | h1 ping-pong | h2 ping-pong | tok
  float* xT = (float*)d_ws;
  float* h1buf = xT + (size_t)TT * EE * 64;
  float* h2buf = h1buf + 2 * HH * BB;
  int* tok = (int*)(h2buf + 2 * HH * BB);
  // Overlays on dead storage:
  //  - eflags: out probs rows (b=1, t=1..) — dead until decoder d<=2 C-phase
  //    (runs after the encoder completed). 512 words, zeroed by k_init.
  //  - dflags: xT[0..255] — group g's words = its own k4=0 slice of xT[t=0];
  //    zeroed group-locally inside k_enc at t==2. 8x32 words.
  unsigned* eflags = (unsigned*)(out + ((size_t)1 * TT + 1) * VV);
  unsigned* dflags = (unsigned*)xT;

  k_init<<<64, 256, 0, stream>>>(out, h1buf, h2buf, tok, eflags);
  k_xgemm<<<TT, 256, 0, stream>>>(input, e_emb, xT);
  k_enc<<<512, 256, 0, stream>>>(xT, h1buf, h2buf,
      eWih0, eWhh0, ebih0, ebhh0, eWih1, eWhh1, ebih1, ebhh1, eflags, dflags);
  k_dec<<<256, 256, 0, stream>>>(h1buf, h2buf, d_emb,
      dWih0, dWhh0, dbih0, dbhh0, dWih1, dWhh1, dbih1, dbhh1,
      Wp1, bp1, Wp2, bp2, out, tok, dflags);
}